// Round 2
// baseline (14196.170 us; speedup 1.0000x reference)
//
#include <hip/hip_runtime.h>
#include <math.h>

typedef _Float16 f16;
typedef _Float16 f16x8 __attribute__((ext_vector_type(8)));
typedef float f32x4 __attribute__((ext_vector_type(4)));

// ---------------- prep kernels ----------------

// traj[0] = x0 (fp32), x0 split into hi/lo f16
__global__ __launch_bounds__(256) void prep_copy_x0(const float* __restrict__ x0,
                                                    float* __restrict__ traj,
                                                    f16* __restrict__ xhi,
                                                    f16* __restrict__ xlo) {
    int i = blockIdx.x * 256 + threadIdx.x;  // 65536 total
    float v = x0[i];
    traj[i] = v;
    f16 h = (f16)v;
    xhi[i] = h;
    xlo[i] = (f16)(v - (float)h);
}

// fp32 -> (hi, lo) f16 split
__global__ __launch_bounds__(256) void prep_cast2(const float* __restrict__ src,
                                                  f16* __restrict__ hi,
                                                  f16* __restrict__ lo) {
    int i = blockIdx.x * 256 + threadIdx.x;
    float v = src[i];
    f16 h = (f16)v;
    hi[i] = h;
    lo[i] = (f16)(v - (float)h);
}

// b1[j] = b_ih[j] + b_hh[j];  bcmb[j] = b1[j] + sum_o b_fc[o] * W_ih[j][o]
__global__ __launch_bounds__(256) void prep_bias(const float* __restrict__ bih,
                                                 const float* __restrict__ bhh,
                                                 const float* __restrict__ bfc,
                                                 const float* __restrict__ Wih,
                                                 float* __restrict__ b1,
                                                 float* __restrict__ bcmb) {
    int wave = blockIdx.x * 4 + (threadIdx.x >> 6);  // 64 waves total
    int lane = threadIdx.x & 63;
    for (int j = wave * 16; j < wave * 16 + 16; ++j) {
        float s = 0.f;
        for (int o = lane; o < 256; o += 64) s += bfc[o] * Wih[j * 256 + o];
        for (int off = 32; off; off >>= 1) s += __shfl_down(s, off);
        if (lane == 0) {
            float t = bih[j] + bhh[j];
            b1[j] = t;
            bcmb[j] = t + s;
        }
    }
}

// Bt[j][k] = W_hh[j][k] + sum_o W_ih[j][o] * W_fc[o][k]  (fp32), split hi/lo
__global__ __launch_bounds__(256) void prep_wcmb(const float* __restrict__ Wih,
                                                 const float* __restrict__ Wfc,
                                                 const float* __restrict__ Whh,
                                                 f16* __restrict__ Bt_hi,
                                                 f16* __restrict__ Bt_lo) {
    __shared__ float As[64][65];
    __shared__ float Bs[64][65];
    int j0 = blockIdx.y * 64, k0 = blockIdx.x * 64;
    int tid = threadIdx.x;
    float acc[4][4] = {};
    for (int o0 = 0; o0 < 256; o0 += 64) {
        __syncthreads();
        #pragma unroll
        for (int i = 0; i < 16; ++i) {
            int e = i * 256 + tid;
            int r = e >> 6, c = e & 63;
            As[r][c] = Wih[(j0 + r) * 256 + o0 + c];
            Bs[r][c] = Wfc[(o0 + r) * 1024 + k0 + c];
        }
        __syncthreads();
        int ty = tid >> 4, tx = tid & 15;
        for (int o = 0; o < 64; ++o) {
            float a[4], b[4];
            #pragma unroll
            for (int i = 0; i < 4; ++i) a[i] = As[ty * 4 + i][o];
            #pragma unroll
            for (int i = 0; i < 4; ++i) b[i] = Bs[o][tx * 4 + i];
            #pragma unroll
            for (int i = 0; i < 4; ++i)
                #pragma unroll
                for (int jj = 0; jj < 4; ++jj) acc[i][jj] += a[i] * b[jj];
        }
    }
    int ty = tid >> 4, tx = tid & 15;
    #pragma unroll
    for (int i = 0; i < 4; ++i)
        #pragma unroll
        for (int jj = 0; jj < 4; ++jj) {
            int j = j0 + ty * 4 + i, k = k0 + tx * 4 + jj;
            float v = acc[i][jj] + Whh[j * 1024 + k];
            f16 h = (f16)v;
            Bt_hi[j * 1024 + k] = h;
            Bt_lo[j * 1024 + k] = (f16)(v - (float)h);
        }
}

// ---------------- step kernel ----------------
// C[256, N] = A[256, KDIM] @ B, B transposed (Bt[n][k]), double-f16 operands:
// C = Ah*Bh + Ah*Bl + Al*Bh  (fp32 MFMA accumulate).
// Columns < 1024: h = tanh(C + bias_h), stored split hi/lo.
// Columns >= 1024 (o = n-1024): y_out[b][o] = C + bias_y[o] as fp32.
// WG = 256 threads (4 waves, 2x2), tile 32(M) x 64(N). grid = (gN, 8).
template <int KDIM, bool HAS_H, bool HAS_Y>
__global__ __launch_bounds__(256) void step_kernel(const f16* __restrict__ Ah,
                                                   const f16* __restrict__ Al,
                                                   const f16* __restrict__ Bh,
                                                   const f16* __restrict__ Bl,
                                                   const float* __restrict__ bias_h,
                                                   f16* __restrict__ h_hi,
                                                   f16* __restrict__ h_lo,
                                                   const float* __restrict__ bias_y,
                                                   float* __restrict__ y_out,
                                                   int n_base) {
    int m0 = blockIdx.y * 32;
    int n0 = n_base + blockIdx.x * 64;
    int tid = threadIdx.x;
    int lane = tid & 63;
    int wid = tid >> 6;
    int wr = wid >> 1;  // 0..1 -> M half
    int wc = wid & 1;   // 0..1 -> N half
    int l15 = lane & 15;
    int klo = (lane >> 4) * 8;  // 0,8,16,24

    size_t aoff = (size_t)(m0 + wr * 16 + l15) * KDIM + klo;
    size_t b0off = (size_t)(n0 + wc * 32 + l15) * KDIM + klo;
    size_t b1off = b0off + (size_t)16 * KDIM;

    f32x4 acc0 = {0.f, 0.f, 0.f, 0.f};
    f32x4 acc1 = {0.f, 0.f, 0.f, 0.f};

    #pragma unroll 4
    for (int kk = 0; kk < KDIM; kk += 32) {
        f16x8 ah = *(const f16x8*)(Ah + aoff + kk);
        f16x8 al = *(const f16x8*)(Al + aoff + kk);
        f16x8 b0h = *(const f16x8*)(Bh + b0off + kk);
        f16x8 b0l = *(const f16x8*)(Bl + b0off + kk);
        f16x8 b1h = *(const f16x8*)(Bh + b1off + kk);
        f16x8 b1l = *(const f16x8*)(Bl + b1off + kk);
        acc0 = __builtin_amdgcn_mfma_f32_16x16x32_f16(ah, b0h, acc0, 0, 0, 0);
        acc0 = __builtin_amdgcn_mfma_f32_16x16x32_f16(ah, b0l, acc0, 0, 0, 0);
        acc0 = __builtin_amdgcn_mfma_f32_16x16x32_f16(al, b0h, acc0, 0, 0, 0);
        acc1 = __builtin_amdgcn_mfma_f32_16x16x32_f16(ah, b1h, acc1, 0, 0, 0);
        acc1 = __builtin_amdgcn_mfma_f32_16x16x32_f16(ah, b1l, acc1, 0, 0, 0);
        acc1 = __builtin_amdgcn_mfma_f32_16x16x32_f16(al, b1h, acc1, 0, 0, 0);
    }

    // D layout: col = lane&15, row = (lane>>4)*4 + reg
    int erow = m0 + wr * 16 + (lane >> 4) * 4;
    int ecol0 = n0 + wc * 32 + l15;

    #pragma unroll
    for (int r = 0; r < 4; ++r) {
        int rr = erow + r;
        #pragma unroll
        for (int half = 0; half < 2; ++half) {
            int c = ecol0 + half * 16;
            float v = half ? acc1[r] : acc0[r];
            if (c < 1024) {
                if (HAS_H) {
                    float t = tanhf(v + bias_h[c]);
                    f16 th = (f16)t;
                    h_hi[rr * 1024 + c] = th;
                    h_lo[rr * 1024 + c] = (f16)(t - (float)th);
                }
            } else if (HAS_Y) {
                y_out[rr * 256 + (c - 1024)] = v + bias_y[c - 1024];
            }
        }
    }
}

// ---------------- launch ----------------

extern "C" void kernel_launch(void* const* d_in, const int* in_sizes, int n_in,
                              void* d_out, int out_size, void* d_ws, size_t ws_size,
                              hipStream_t stream) {
    const float* x0 = (const float*)d_in[0];
    const float* Wih = (const float*)d_in[1];
    const float* bih = (const float*)d_in[2];
    const float* Whh = (const float*)d_in[3];
    const float* bhh = (const float*)d_in[4];
    const float* Wfc = (const float*)d_in[5];
    const float* bfc = (const float*)d_in[6];
    float* traj = (float*)d_out;  // [512][256][256]

    char* w = (char*)d_ws;
    size_t off = 0;
    f16* Bt_hi = (f16*)(w + off); off += 1280u * 1024 * 2;   // 2,621,440
    f16* Bt_lo = (f16*)(w + off); off += 1280u * 1024 * 2;
    f16* Wih_hi = (f16*)(w + off); off += 1024u * 256 * 2;   // 524,288
    f16* Wih_lo = (f16*)(w + off); off += 1024u * 256 * 2;
    f16* x0_hi = (f16*)(w + off); off += 256u * 256 * 2;     // 131,072
    f16* x0_lo = (f16*)(w + off); off += 256u * 256 * 2;
    f16* hb_hi[2]; f16* hb_lo[2];
    hb_hi[0] = (f16*)(w + off); off += 256u * 1024 * 2;      // 524,288
    hb_lo[0] = (f16*)(w + off); off += 256u * 1024 * 2;
    hb_hi[1] = (f16*)(w + off); off += 256u * 1024 * 2;
    hb_lo[1] = (f16*)(w + off); off += 256u * 1024 * 2;
    float* b1 = (float*)(w + off); off += 4096;
    float* bcmb = (float*)(w + off); off += 4096;

    // prep
    prep_copy_x0<<<dim3(256), dim3(256), 0, stream>>>(x0, traj, x0_hi, x0_lo);
    prep_cast2<<<dim3(1024), dim3(256), 0, stream>>>(Wih, Wih_hi, Wih_lo);
    prep_cast2<<<dim3(1024), dim3(256), 0, stream>>>(Wfc, Bt_hi + 1024 * 1024,
                                                     Bt_lo + 1024 * 1024);
    prep_bias<<<dim3(16), dim3(256), 0, stream>>>(bih, bhh, bfc, Wih, b1, bcmb);
    prep_wcmb<<<dim3(16, 16), dim3(256), 0, stream>>>(Wih, Wfc, Whh, Bt_hi, Bt_lo);

    // step 1: h_1 = tanh(x0 @ W_ih^T + b_ih + b_hh) -> hb[1]
    step_kernel<256, true, false><<<dim3(16, 8), dim3(256), 0, stream>>>(
        x0_hi, x0_lo, Wih_hi, Wih_lo, b1, hb_hi[1], hb_lo[1], nullptr, nullptr, 0);

    // steps 2..511: h_t = tanh(h_{t-1} @ W_cmb + b_cmb); y_{t-1} = h_{t-1} @ W_fc^T + b_fc
    for (int t = 2; t <= 511; ++t) {
        step_kernel<1024, true, true><<<dim3(20, 8), dim3(256), 0, stream>>>(
            hb_hi[(t - 1) & 1], hb_lo[(t - 1) & 1], Bt_hi, Bt_lo, bcmb,
            hb_hi[t & 1], hb_lo[t & 1], bfc,
            traj + (size_t)(t - 1) * 65536, 0);
    }

    // final: y_511 = h_511 @ W_fc^T + b_fc -> traj[511]
    step_kernel<1024, false, true><<<dim3(4, 8), dim3(256), 0, stream>>>(
        hb_hi[1], hb_lo[1], Bt_hi, Bt_lo, nullptr, nullptr, nullptr, bfc,
        traj + (size_t)511 * 65536, 1024);
}